// Round 5
// baseline (812.220 us; speedup 1.0000x reference)
//
#include <hip/hip_runtime.h>
#include <hip/hip_cooperative_groups.h>
#include <hip/hip_bf16.h>
#include <math.h>

namespace cg = cooperative_groups;

// Laplacian-pyramid L1 loss, (2,1,64,256,256), 5 levels, sigma=1 (9-tap), scipy-reflect.
// loss = sum_l mean |lap_pyramid(input-target)[l]| (linearity). Single cooperative
// mega-kernel: 13 phases separated by grid.sync() instead of 13 launches.

struct GW { float w[9]; float A, B; };

struct Params {
    const float* in; const float* tg;
    float* T1; float* V;
    float* C1; float* C2; float* C3; float* C4; float* C5;
    float* P; float* out;
    __hip_bfloat16* DIFF; int use_diff;
    GW g;
};

__device__ __forceinline__ int ridx(int p, int n) {
    // scipy 'reflect' (symmetric) for power-of-two n; valid for p >= -2n
    int m = 2 * n;
    int q = (p + m) & (m - 1);
    return (q < n) ? q : (m - 1 - q);
}

__device__ __forceinline__ void fma4(float4& a, float w, const float4 b) {
    a.x = fmaf(w, b.x, a.x); a.y = fmaf(w, b.y, a.y);
    a.z = fmaf(w, b.z, a.z); a.w = fmaf(w, b.w, a.w);
}

__device__ __forceinline__ float block_sum256(float v) {
    #pragma unroll
    for (int off = 32; off > 0; off >>= 1) v += __shfl_down(v, off, 64);
    __shared__ float wp[4];
    int tid = threadIdx.x;
    if ((tid & 63) == 0) wp[tid >> 6] = v;
    __syncthreads();
    return wp[0] + wp[1] + wp[2] + wp[3];
}

// ---------------------------------------------------------------------------
// k1: fused W+H gaussian on (H,W) slices, emitting only even (y,x) -> (Hd,Wd).
// Tile 64x16 in downsampled space. smem: raw[40][136] + mid[40][64] = 8000 floats.
template<bool DIFF_IN, bool WRITE_DIFF>
__device__ void dev_k1_slice(const float* __restrict__ inA, const float* __restrict__ inB,
                             float* __restrict__ out, __hip_bfloat16* __restrict__ diff,
                             int x0d, int y0d, int slice, int H, int W, int Hd, int Wd,
                             const GW& g, float* smem)
{
    float* raw = smem;               // [40][136]
    float* mid = smem + 40*136;      // [40][64]
    const size_t in_off  = (size_t)slice * H * W;
    const size_t out_off = (size_t)slice * Hd * Wd;
    const int tid = threadIdx.x;
    const int gy0 = 2*y0d - 4, gx0 = 2*x0d - 4;
    __syncthreads();                 // protect smem reuse across calls/phases
    if (2*x0d + 127 < W) {
        // float4 for cols 4..131 (aligned), scalar reflect for the 8 halo cols
        for (int i = tid; i < 40*32; i += 256) {
            int rr = i >> 5, c4 = (i & 31) + 1;
            int gy = ridx(gy0 + rr, H);
            size_t base = in_off + (size_t)gy * W + gx0 + 4*c4;
            float4 v = *(const float4*)(inA + base);
            if (DIFF_IN) {
                float4 bb = *(const float4*)(inB + base);
                v.x -= bb.x; v.y -= bb.y; v.z -= bb.z; v.w -= bb.w;
            }
            *(float4*)&raw[rr*136 + 4*c4] = v;
        }
        for (int i = tid; i < 40*8; i += 256) {
            int rr = i >> 3, j = i & 7;
            int cc = (j < 4) ? j : (128 + j);
            int gy = ridx(gy0 + rr, H);
            int gx = ridx(gx0 + cc, W);
            size_t idx = in_off + (size_t)gy * W + gx;
            float v = inA[idx];
            if (DIFF_IN) v -= inB[idx];
            raw[rr*136 + cc] = v;
        }
    } else {
        for (int i = tid; i < 40*136; i += 256) {
            int rr = i / 136, cc = i - rr*136;
            int gy = ridx(gy0 + rr, H);
            int gx = ridx(gx0 + cc, W);
            size_t idx = in_off + (size_t)gy * W + gx;
            float v = inA[idx];
            if (DIFF_IN) v -= inB[idx];
            raw[rr*136 + cc] = v;
        }
    }
    __syncthreads();
    if (WRITE_DIFF) {
        // owned full-res region raw[4..36)[4..132) -> bf16 diff
        for (int i = tid; i < 32*128; i += 256) {
            int r = i >> 7, c = i & 127;
            diff[in_off + (size_t)(2*y0d + r) * W + (2*x0d + c)] =
                __float2bfloat16(raw[(4+r)*136 + 4 + c]);
        }
    }
    for (int i = tid; i < 40*64; i += 256) {
        int rr = i >> 6, c = i & 63;
        float s = 0.f;
        #pragma unroll
        for (int k = 0; k < 9; ++k) s = fmaf(g.w[k], raw[rr*136 + 2*c + k], s);
        mid[rr*64 + c] = s;
    }
    __syncthreads();
    {
        int r = tid >> 6, c = tid & 63;
        int ox = x0d + c;
        #pragma unroll
        for (int j = 0; j < 4; ++j) {
            int oy = y0d + r*4 + j;
            if (oy < Hd && ox < Wd) {
                int rb = 2*(oy - y0d);
                float s = 0.f;
                #pragma unroll
                for (int k = 0; k < 9; ++k) s = fmaf(g.w[k], mid[(rb+k)*64 + c], s);
                out[out_off + (size_t)oy * Wd + ox] = s;
            }
        }
    }
}

// ---------------------------------------------------------------------------
// k2: D-axis gaussian + batch(2) reflect mix, at even z -> down. One float4/elem.
__device__ void dev_k2_elem(long i, const float4* __restrict__ T, float4* __restrict__ O,
                            int D, int Dd, int M4, const GW& g)
{
    int zd = (int)(i / M4);
    int q  = (int)(i - (long)zd * M4);
    float4 s0 = {0,0,0,0}, s1 = {0,0,0,0};
    if (2*zd - 4 >= 0 && 2*zd + 4 < D) {
        #pragma unroll
        for (int k = 0; k < 9; ++k) {
            int zk = 2*zd - 4 + k;
            fma4(s0, g.w[k], T[(size_t)zk * M4 + q]);
            fma4(s1, g.w[k], T[(size_t)(D + zk) * M4 + q]);
        }
    } else {
        #pragma unroll
        for (int k = 0; k < 9; ++k) {
            int zk = ridx(2*zd - 4 + k, D);
            fma4(s0, g.w[k], T[(size_t)zk * M4 + q]);
            fma4(s1, g.w[k], T[(size_t)(D + zk) * M4 + q]);
        }
    }
    float4 o0, o1;
    o0.x = g.A*s0.x + g.B*s1.x; o0.y = g.A*s0.y + g.B*s1.y;
    o0.z = g.A*s0.z + g.B*s1.z; o0.w = g.A*s0.w + g.B*s1.w;
    o1.x = g.B*s0.x + g.A*s1.x; o1.y = g.B*s0.y + g.A*s1.y;
    o1.z = g.B*s0.z + g.A*s1.z; o1.w = g.B*s0.w + g.A*s1.w;
    O[(size_t)zd * M4 + q] = o0;
    O[(size_t)(Dd + zd) * M4 + q] = o1;
}

// ---------------------------------------------------------------------------
// k3: D-filter of zero-stuffed dn + batch mix (D/batch part of upsample), x8.
__device__ void dev_k3_elem(long i, const float4* __restrict__ Dn, float4* __restrict__ O,
                            int D, int Dd, int M4, const GW& g)
{
    int z = (int)(i / M4);
    int q = (int)(i - (long)z * M4);
    float4 s0 = {0,0,0,0}, s1 = {0,0,0,0};
    if (z >= 4 && z + 4 < D) {
        if ((z & 1) == 0) {
            int base = (z >> 1) - 2;
            #pragma unroll
            for (int kk = 0; kk < 5; ++kk) {
                fma4(s0, g.w[2*kk], Dn[(size_t)(base + kk) * M4 + q]);
                fma4(s1, g.w[2*kk], Dn[(size_t)(Dd + base + kk) * M4 + q]);
            }
        } else {
            int base = (z - 3) >> 1;
            #pragma unroll
            for (int kk = 0; kk < 4; ++kk) {
                fma4(s0, g.w[2*kk+1], Dn[(size_t)(base + kk) * M4 + q]);
                fma4(s1, g.w[2*kk+1], Dn[(size_t)(Dd + base + kk) * M4 + q]);
            }
        }
    } else {
        #pragma unroll
        for (int k = 0; k < 9; ++k) {
            int zk = ridx(z - 4 + k, D);
            if ((zk & 1) == 0) {
                int j = zk >> 1;
                fma4(s0, g.w[k], Dn[(size_t)j * M4 + q]);
                fma4(s1, g.w[k], Dn[(size_t)(Dd + j) * M4 + q]);
            }
        }
    }
    float4 o0, o1;
    o0.x = 8.f*(g.A*s0.x + g.B*s1.x); o0.y = 8.f*(g.A*s0.y + g.B*s1.y);
    o0.z = 8.f*(g.A*s0.z + g.B*s1.z); o0.w = 8.f*(g.A*s0.w + g.B*s1.w);
    o1.x = 8.f*(g.B*s0.x + g.A*s1.x); o1.y = 8.f*(g.B*s0.y + g.A*s1.y);
    o1.z = 8.f*(g.B*s0.z + g.A*s1.z); o1.w = 8.f*(g.B*s0.w + g.A*s1.w);
    O[(size_t)z * M4 + q] = o0;
    O[(size_t)(D + z) * M4 + q] = o1;
}

// ---------------------------------------------------------------------------
// k4: up = H-filter(even-row parity) o W-filter of V; returns per-thread sum|cur-up|.
// Tile 64x32 outputs. CK: 0 = fp32 cur; 1 = bf16 diff; 2 = fp32 pair (in - tg).
template<int CK>
__device__ float dev_k4_slice(const float* __restrict__ V,
                              const float* __restrict__ curF, const float* __restrict__ curF2,
                              const __hip_bfloat16* __restrict__ curH,
                              int x0, int y0, int slice, int H, int W, int Hd, int Wd,
                              const GW& g, float* smem)
{
    float* vt   = smem;            // [20][72]
    float* mid4 = smem + 20*72;    // [20][64]
    const size_t v_off = (size_t)slice * Hd * Wd;
    const size_t c_off = (size_t)slice * H * W;
    const int tid = threadIdx.x;
    const int vy0 = (y0 >> 1) - 2;
    __syncthreads();               // protect smem reuse
    for (int i = tid; i < 20*72; i += 256) {
        int rr = i / 72, cc = i - rr*72;
        int vy = vy0 + rr;
        int tx = x0 - 4 + cc;
        if (tx < 0) tx = -1 - tx;      // left reflect lands in [0,3] < Wd
        float v = 0.f;
        if (vy >= 0 && vy < Hd && tx < Wd) v = V[v_off + (size_t)vy * Wd + tx];
        vt[rr*72 + cc] = v;            // x >= Wd region of t is zero
    }
    __syncthreads();
    for (int i = tid; i < 20*64; i += 256) {
        int rr = i >> 6, c = i & 63;
        float s = 0.f;
        #pragma unroll
        for (int k = 0; k < 9; ++k) s = fmaf(g.w[k], vt[rr*72 + c + k], s);
        mid4[rr*64 + c] = s;
    }
    __syncthreads();
    const bool yin = (y0 >= 4) && (y0 + 35 < H);
    const int c = tid & 63;
    const int ry_base = (tid >> 6) * 8;
    const int ox = x0 + c;
    float lsum = 0.f;
    #pragma unroll
    for (int j = 0; j < 8; ++j) {
        int ry = ry_base + j;          // parity(ry) == parity(j)
        int oy = y0 + ry;
        if (ox < W && oy < H) {
            float s = 0.f;
            if (yin) {
                if ((j & 1) == 0) {
                    int r0 = ry >> 1;
                    s = g.w[0]*mid4[r0*64+c] + g.w[2]*mid4[(r0+1)*64+c] + g.w[4]*mid4[(r0+2)*64+c]
                      + g.w[6]*mid4[(r0+3)*64+c] + g.w[8]*mid4[(r0+4)*64+c];
                } else {
                    int r0 = ((ry - 3) >> 1) + 2;
                    s = g.w[1]*mid4[r0*64+c] + g.w[3]*mid4[(r0+1)*64+c]
                      + g.w[5]*mid4[(r0+2)*64+c] + g.w[7]*mid4[(r0+3)*64+c];
                }
            } else {
                #pragma unroll
                for (int k = 0; k < 9; ++k) {
                    int gy = ridx(oy - 4 + k, H);
                    if ((gy & 1) == 0) s = fmaf(g.w[k], mid4[((gy>>1) - vy0)*64 + c], s);
                }
            }
            size_t idx = c_off + (size_t)oy * W + ox;
            float cv;
            if (CK == 0)      cv = curF[idx];
            else if (CK == 1) cv = __bfloat162float(curH[idx]);
            else              cv = curF[idx] - curF2[idx];
            lsum += fabsf(cv - s);
        }
    }
    return lsum;
}

// ---------------------------------------------------------------------------
__global__ __launch_bounds__(256, 4)
void mega(Params p)
{
    cg::grid_group gg = cg::this_grid();
    __shared__ float smem[40*136 + 40*64];
    const int G = (int)gridDim.x, b = (int)blockIdx.x, tid = threadIdx.x;
    const GW g = p.g;
    float* C[6] = { nullptr, p.C1, p.C2, p.C3, p.C4, p.C5 };
    const int Dl[5] = {64,32,16,8,4}, Hl[5] = {256,128,64,32,16}, Wl[5] = {256,128,64,32,16};

    // P0: k1(0) (+bf16 diff)
    {
        const int npt = 2*8, nt = npt*128;
        for (int t = b; t < nt; t += G) {
            int s = t / npt, r = t - s*npt, ty = r >> 1, tx = r & 1;
            if (p.use_diff)
                dev_k1_slice<true,true >(p.in, p.tg, p.T1, p.DIFF, tx*64, ty*16, s, 256,256,128,128, g, smem);
            else
                dev_k1_slice<true,false>(p.in, p.tg, p.T1, nullptr, tx*64, ty*16, s, 256,256,128,128, g, smem);
        }
    }
    gg.sync();
    // P1: k2(0): T1 -> C1
    {
        const int M4 = 128*128/4; const long n = (long)32 * M4;
        for (long i = (long)b*256 + tid; i < n; i += (long)G*256)
            dev_k2_elem(i, (const float4*)p.T1, (float4*)p.C1, 64, 32, M4, g);
    }
    gg.sync();

    for (int l = 0; l < 4; ++l) {
        const int D = Dl[l], H = Hl[l], W = Wl[l];
        const int Dd = D>>1, Hd = H>>1, Wd = W>>1, M4 = (Hd*Wd)>>2;
        const int D2 = Dl[l+1], H2 = Hl[l+1], W2 = Wl[l+1];
        const int Dd2 = D2>>1, Hd2 = H2>>1, Wd2 = W2>>1, M42 = (Hd2*Wd2)>>2;
        // FATA: k3(l) [C[l+1] -> V]  +  k1(l+1) [C[l+1] -> T1]
        {
            const long n = (long)D * M4;
            for (long i = (long)b*256 + tid; i < n; i += (long)G*256)
                dev_k3_elem(i, (const float4*)C[l+1], (float4*)p.V, D, Dd, M4, g);
            const int ntx = (Wd2 + 63) >> 6, nty = (Hd2 + 15) >> 4;
            const int npt = ntx*nty, nt = npt * 2*D2;
            for (int t = b; t < nt; t += G) {
                int s = t / npt, r = t - s*npt, ty = r / ntx, tx = r - ty*ntx;
                dev_k1_slice<false,false>(C[l+1], nullptr, p.T1, nullptr,
                                          tx*64, ty*16, s, H2, W2, Hd2, Wd2, g, smem);
            }
        }
        gg.sync();
        // FATB: k2(l+1) [T1 -> C[l+2]]  +  k4(l) [V,cur(l) -> P]
        {
            const long n = (long)Dd2 * M42;
            for (long i = (long)b*256 + tid; i < n; i += (long)G*256)
                dev_k2_elem(i, (const float4*)p.T1, (float4*)C[l+2], D2, Dd2, M42, g);
            float acc = 0.f;
            const int ntx = (W + 63) >> 6, nty = (H + 31) >> 5;
            const int npt = ntx*nty, nt = npt * 2*D;
            for (int t = b; t < nt; t += G) {
                int s = t / npt, r = t - s*npt, ty = r / ntx, tx = r - ty*ntx;
                if (l == 0) {
                    if (p.use_diff)
                        acc += dev_k4_slice<1>(p.V, nullptr, nullptr, p.DIFF,
                                               tx*64, ty*32, s, H, W, Hd, Wd, g, smem);
                    else
                        acc += dev_k4_slice<2>(p.V, p.in, p.tg, nullptr,
                                               tx*64, ty*32, s, H, W, Hd, Wd, g, smem);
                } else {
                    acc += dev_k4_slice<0>(p.V, C[l], nullptr, nullptr,
                                           tx*64, ty*32, s, H, W, Hd, Wd, g, smem);
                }
            }
            float tot = block_sum256(acc);
            if (tid == 0) p.P[l*G + b] = tot / ((float)(2*D) * H * W);
        }
        gg.sync();
    }
    // P10: k3(4): C5 -> V
    {
        const long n = 4 * 16;  // D=4, M4=16
        for (long i = (long)b*256 + tid; i < n; i += (long)G*256)
            dev_k3_elem(i, (const float4*)p.C5, (float4*)p.V, 4, 2, 16, g);
    }
    gg.sync();
    // P11: k4(4): 8 slices
    {
        float acc = 0.f;
        for (int t = b; t < 8; t += G)
            acc += dev_k4_slice<0>(p.V, p.C4, nullptr, nullptr, 0, 0, t, 16, 16, 8, 8, g, smem);
        float tot = block_sum256(acc);
        if (tid == 0) p.P[4*G + b] = tot / (8.f * 16.f * 16.f);
    }
    gg.sync();
    // P12: final reduce (block 0)
    if (b == 0) {
        const int n = 5 * G;
        float s = 0.f;
        for (int i = tid; i < n; i += 256) s += p.P[i];
        float tot = block_sum256(s);
        if (tid == 0) p.out[0] = tot;
    }
}

// ---------------------------------------------------------------------------
extern "C" void kernel_launch(void* const* d_in, const int* in_sizes, int n_in,
                              void* d_out, int out_size, void* d_ws, size_t ws_size,
                              hipStream_t stream)
{
    const float* in = (const float*)d_in[0];
    const float* tg = (const float*)d_in[1];
    float* out = (float*)d_out;

    GW g;
    {
        double u[9], S = 0.0;
        for (int k = 0; k < 9; ++k) { double d = k - 4; u[k] = exp(-0.5 * d * d); S += u[k]; }
        for (int k = 0; k < 9; ++k) g.w[k] = (float)(u[k] / S);
        g.A = (float)((2.0*u[0] + u[1] + u[3] + u[4]) / S);  // batch(2) reflect self-weight
        g.B = (float)((u[1] + 2.0*u[2] + u[3]) / S);         // cross-weight
    }

    // workspace layout (floats)
    float* T1 = (float*)d_ws;          // 2*64*128*128 = 2097152
    float* V  = T1 + 2097152;          // 2097152
    float* C1 = V  + 2097152;          // 1048576
    float* C2 = C1 + 1048576;          // 131072
    float* C3 = C2 + 131072;           // 16384
    float* C4 = C3 + 16384;            // 2048
    float* C5 = C4 + 2048;             // 256
    float* P  = C5 + 256;              // 5*2048 max partials
    const int np_cap = 5 * 2048;
    __hip_bfloat16* DIFF = (__hip_bfloat16*)(P + np_cap);
    const size_t diff_elems = (size_t)2 * 64 * 256 * 256;   // 8388608
    const size_t need = ((size_t)(P - T1) + np_cap) * sizeof(float) + diff_elems * 2;
    const int use_diff = (ws_size >= need) ? 1 : 0;

    Params prm;
    prm.in = in; prm.tg = tg;
    prm.T1 = T1; prm.V = V;
    prm.C1 = C1; prm.C2 = C2; prm.C3 = C3; prm.C4 = C4; prm.C5 = C5;
    prm.P = P; prm.out = out;
    prm.DIFF = use_diff ? DIFF : nullptr; prm.use_diff = use_diff;
    prm.g = g;

    int nblk = 0;
    if (hipOccupancyMaxActiveBlocksPerMultiprocessor(&nblk, mega, 256, 0) != hipSuccess || nblk < 1)
        nblk = 1;
    long gmax = (long)nblk * 256;      // 256 CUs on MI355X
    int grid = (gmax >= 2048) ? 2048 : ((gmax >= 1024) ? 1024 : (int)gmax);

    void* args[] = { &prm };
    hipLaunchCooperativeKernel(reinterpret_cast<void*>(mega), dim3(grid), dim3(256),
                               args, 0, stream);
}

// Round 6
// 336.891 us; speedup vs baseline: 2.4109x; 2.4109x over previous
//
#include <hip/hip_runtime.h>
#include <hip/hip_bf16.h>
#include <math.h>

// Laplacian-pyramid L1 loss, (2,1,64,256,256), 5 levels, sigma=1 (9-tap), scipy-reflect.
// loss = sum_l mean |lap_pyramid(input-target)[l]| (linearity of the pyramid).
// 8 launches: k1l0 -> k2l0 -> k12(1..4, tiny) -> k4p(ALL levels, fused k3+k4) -> reduce.

struct GW { float w[9]; float A, B; };

__device__ __forceinline__ int ridx(int p, int n) {
    // scipy 'reflect' (symmetric) for power-of-two n; valid for p >= -2n
    int m = 2 * n;
    int q = (p + m) & (m - 1);
    return (q < n) ? q : (m - 1 - q);
}

__device__ __forceinline__ float block_sum256(float v) {
    #pragma unroll
    for (int off = 32; off > 0; off >>= 1) v += __shfl_down(v, off, 64);
    __shared__ float wp[4];
    int tid = threadIdx.x;
    if ((tid & 63) == 0) wp[tid >> 6] = v;
    __syncthreads();
    return wp[0] + wp[1] + wp[2] + wp[3];
}

// ---------------------------------------------------------------------------
// k1l0: level-0 fused W+H gaussian of (in - tg), emitting even (y,x) -> T1.
// Also (optionally) writes bf16 DIFF = in - tg for k4p's level-0 cur read.
// Tile 64x16 in downsampled space; grid (2, 8, 128). All tiles x-fast-path at l0.
template<bool WDIFF>
__global__ __launch_bounds__(256)
void k1l0(const float* __restrict__ in, const float* __restrict__ tg,
          float* __restrict__ T1, __hip_bfloat16* __restrict__ DIFF, GW g)
{
    const int H = 256, W = 256, Hd = 128, Wd = 128;
    const int x0d = blockIdx.x * 64, y0d = blockIdx.y * 16, slice = blockIdx.z;
    __shared__ float raw[40][136];
    __shared__ float mid[40][64];
    const size_t in_off  = (size_t)slice * H * W;
    const size_t out_off = (size_t)slice * Hd * Wd;
    const int tid = threadIdx.x;
    const int gy0 = 2*y0d - 4, gx0 = 2*x0d - 4;
    // float4 body (cols 4..131), scalar reflect halos (cols 0..3, 132..135)
    for (int i = tid; i < 40*32; i += 256) {
        int rr = i >> 5, c4 = (i & 31) + 1;
        int gy = ridx(gy0 + rr, H);
        size_t base = in_off + (size_t)gy * W + gx0 + 4*c4;
        float4 v = *(const float4*)(in + base);
        float4 b = *(const float4*)(tg + base);
        v.x -= b.x; v.y -= b.y; v.z -= b.z; v.w -= b.w;
        *(float4*)&raw[rr][4*c4] = v;
    }
    for (int i = tid; i < 40*8; i += 256) {
        int rr = i >> 3, j = i & 7;
        int cc = (j < 4) ? j : (128 + j);
        int gy = ridx(gy0 + rr, H);
        int gx = ridx(gx0 + cc, W);
        size_t idx = in_off + (size_t)gy * W + gx;
        raw[rr][cc] = in[idx] - tg[idx];
    }
    __syncthreads();
    if (WDIFF) {
        // owned full-res region raw[4..36)[4..132) -> bf16 diff
        for (int i = tid; i < 32*128; i += 256) {
            int r = i >> 7, c = i & 127;
            DIFF[in_off + (size_t)(2*y0d + r) * W + (2*x0d + c)] =
                __float2bfloat16(raw[4 + r][4 + c]);
        }
    }
    for (int i = tid; i < 40*64; i += 256) {
        int rr = i >> 6, c = i & 63;
        float s = 0.f;
        #pragma unroll
        for (int k = 0; k < 9; ++k) s = fmaf(g.w[k], raw[rr][2*c + k], s);
        mid[rr][c] = s;
    }
    __syncthreads();
    {
        int r = tid >> 6, c = tid & 63;
        int ox = x0d + c;
        #pragma unroll
        for (int j = 0; j < 4; ++j) {
            int oy = y0d + r*4 + j;
            int rb = 2*(r*4 + j);
            float s = 0.f;
            #pragma unroll
            for (int k = 0; k < 9; ++k) s = fmaf(g.w[k], mid[rb + k][c], s);
            T1[out_off + (size_t)oy * Wd + ox] = s;
        }
    }
}

// ---------------------------------------------------------------------------
// k2l0: D-axis gaussian + batch(2) reflect mix of T1 at even z -> C1. float4/elem.
__global__ __launch_bounds__(256)
void k2l0(const float* __restrict__ T1, float* __restrict__ dn,
          int D, int Dd, int M4, GW g)
{
    long i = (long)blockIdx.x * 256 + threadIdx.x;
    if (i >= (long)Dd * M4) return;
    int zd = (int)(i / M4);
    int q  = (int)(i - (long)zd * M4);
    const float4* T = (const float4*)T1;
    float4* O = (float4*)dn;
    float4 s0 = {0,0,0,0}, s1 = {0,0,0,0};
    #pragma unroll
    for (int k = 0; k < 9; ++k) {
        int zk = (2*zd - 4 + k >= 0 && 2*zd - 4 + k < D) ? (2*zd - 4 + k)
                                                         : ridx(2*zd - 4 + k, D);
        float4 a = T[(size_t)zk * M4 + q];
        float4 b = T[(size_t)(D + zk) * M4 + q];
        s0.x = fmaf(g.w[k], a.x, s0.x); s0.y = fmaf(g.w[k], a.y, s0.y);
        s0.z = fmaf(g.w[k], a.z, s0.z); s0.w = fmaf(g.w[k], a.w, s0.w);
        s1.x = fmaf(g.w[k], b.x, s1.x); s1.y = fmaf(g.w[k], b.y, s1.y);
        s1.z = fmaf(g.w[k], b.z, s1.z); s1.w = fmaf(g.w[k], b.w, s1.w);
    }
    float4 o0, o1;
    o0.x = g.A*s0.x + g.B*s1.x; o0.y = g.A*s0.y + g.B*s1.y;
    o0.z = g.A*s0.z + g.B*s1.z; o0.w = g.A*s0.w + g.B*s1.w;
    o1.x = g.B*s0.x + g.A*s1.x; o1.y = g.B*s0.y + g.A*s1.y;
    o1.z = g.B*s0.z + g.A*s1.z; o1.w = g.B*s0.w + g.A*s1.w;
    O[(size_t)zd * M4 + q] = o0;
    O[(size_t)(Dd + zd) * M4 + q] = o1;
}

// ---------------------------------------------------------------------------
// k12: fused full 3D gauss + downsample for SMALL levels: X(2,D,H,W) -> Y(2,Dd,Hd,Wd).
// Block = 64x8 tile in downsampled (x,y), one output zd, both batches.
// Recomputes the WH-filtered slice per z-tap (4.5x) -- negligible at these sizes.
__global__ __launch_bounds__(256)
void k12(const float* __restrict__ X, float* __restrict__ Y,
         int D, int H, int W, GW g)
{
    const int Dd = D >> 1, Hd = H >> 1, Wd = W >> 1;
    const int x0d = blockIdx.x * 64, y0d = blockIdx.y * 8, zd = blockIdx.z;
    __shared__ float raw[24][136];
    __shared__ float mid[24][64];
    const int tid = threadIdx.x;
    const int gy0 = 2*y0d - 4, gx0 = 2*x0d - 4;
    const int r = tid >> 6, c = tid & 63;
    const bool fast = (2*x0d + 127 < W);
    float acc[2][2] = {{0.f,0.f},{0.f,0.f}};
    for (int k = 0; k < 9; ++k) {
        int zs = ridx(2*zd - 4 + k, D);
        float wk = g.w[k];
        for (int b = 0; b < 2; ++b) {
            const float* Xs = X + (size_t)(b*D + zs) * H * W;
            __syncthreads();
            if (fast) {
                for (int i = tid; i < 24*32; i += 256) {
                    int rr = i >> 5, c4 = (i & 31) + 1;
                    int gy = ridx(gy0 + rr, H);
                    *(float4*)&raw[rr][4*c4] =
                        *(const float4*)(Xs + (size_t)gy * W + gx0 + 4*c4);
                }
                for (int i = tid; i < 24*8; i += 256) {
                    int rr = i >> 3, j = i & 7;
                    int cc = (j < 4) ? j : (128 + j);
                    int gy = ridx(gy0 + rr, H), gx = ridx(gx0 + cc, W);
                    raw[rr][cc] = Xs[(size_t)gy * W + gx];
                }
            } else {
                for (int i = tid; i < 24*136; i += 256) {
                    int rr = i / 136, cc = i - rr*136;
                    int gy = ridx(gy0 + rr, H), gx = ridx(gx0 + cc, W);
                    raw[rr][cc] = Xs[(size_t)gy * W + gx];
                }
            }
            __syncthreads();
            for (int i = tid; i < 24*64; i += 256) {
                int rr = i >> 6, cc = i & 63;
                float s = 0.f;
                #pragma unroll
                for (int t = 0; t < 9; ++t) s = fmaf(g.w[t], raw[rr][2*cc + t], s);
                mid[rr][cc] = s;
            }
            __syncthreads();
            #pragma unroll
            for (int j = 0; j < 2; ++j) {
                int rb = 2*(r*2 + j);
                float s = 0.f;
                #pragma unroll
                for (int t = 0; t < 9; ++t) s = fmaf(g.w[t], mid[rb + t][c], s);
                acc[b][j] = fmaf(wk, s, acc[b][j]);
            }
        }
    }
    int ox = x0d + c;
    if (ox < Wd) {
        size_t Msz = (size_t)Hd * Wd;
        #pragma unroll
        for (int j = 0; j < 2; ++j) {
            int oy = y0d + r*2 + j;
            if (oy < Hd) {
                size_t o = (size_t)oy * Wd + ox;
                Y[(size_t)(0*Dd + zd) * Msz + o] = g.A*acc[0][j] + g.B*acc[1][j];
                Y[(size_t)(1*Dd + zd) * Msz + o] = g.B*acc[0][j] + g.A*acc[1][j];
            }
        }
    }
}

// ---------------------------------------------------------------------------
// k4p: ALL levels' loss in one launch. Per block: one 64x32 output tile of one slice
// of one level. Fuses k3 (D-filter+mix of dn, on the fly during vt staging) and k4
// (W/H up-filter + |cur - up| reduce). Writes one scaled partial per block.
struct K4P {
    const float* dn[5];    // dn(l) = C[l+1]
    const float* cur[5];   // l>=1: C[l]
    const float* in; const float* tg;
    const __hip_bfloat16* DIFF;
    float* P;
    int use_diff;
    int bo[6];             // cumulative block offsets per level
    GW g;
};

__global__ __launch_bounds__(256)
void k4p(K4P p)
{
    const int Dt[5] = {64,32,16,8,4}, Ht[5] = {256,128,64,32,16};
    __shared__ float vt[20][72];
    __shared__ float mid[20][64];
    const int bid = (int)blockIdx.x;
    int l = 0;
    while (l < 4 && bid >= p.bo[l+1]) ++l;
    const int local = bid - p.bo[l];
    const int D = Dt[l], H = Ht[l], W = H;
    const int Dd = D >> 1, Hd = H >> 1, Wd = W >> 1, Md = Hd * Wd;
    const int ntx = (W + 63) >> 6, nty = (H + 31) >> 5;
    const int s = local / (ntx*nty);
    const int rem = local - s*(ntx*nty);
    const int ty = rem / ntx, tx = rem - ty*ntx;
    const int x0 = tx*64, y0 = ty*32;
    const int b = s / D, z = s - b*D;
    const GW g = p.g;
    const float* dn0 = p.dn[l] + (size_t)b * Dd * Md;        // own batch
    const float* dn1 = p.dn[l] + (size_t)(1 - b) * Dd * Md;  // other batch
    const int tid = threadIdx.x;
    const int vy0 = (y0 >> 1) - 2;

    // --- stage vt: on-the-fly z-filter + batch mix of dn (replaces V) ---
    const bool zin = (z >= 4) && (z + 4 < D);
    if (zin && !(z & 1)) {
        const int j0 = (z >> 1) - 2;
        for (int i = tid; i < 20*72; i += 256) {
            int rr = i / 72, cc = i - rr*72;
            int vy = vy0 + rr;
            int txx = x0 - 4 + cc;
            if (txx < 0) txx = -1 - txx;
            float v = 0.f;
            if (vy >= 0 && vy < Hd && txx < Wd) {
                size_t o = (size_t)vy * Wd + txx;
                float s0 = 0.f, s1 = 0.f;
                #pragma unroll
                for (int t = 0; t < 5; ++t) {
                    s0 = fmaf(g.w[2*t], dn0[(size_t)(j0 + t) * Md + o], s0);
                    s1 = fmaf(g.w[2*t], dn1[(size_t)(j0 + t) * Md + o], s1);
                }
                v = 8.f * (g.A*s0 + g.B*s1);
            }
            vt[rr][cc] = v;
        }
    } else if (zin) {
        const int j0 = (z - 3) >> 1;
        for (int i = tid; i < 20*72; i += 256) {
            int rr = i / 72, cc = i - rr*72;
            int vy = vy0 + rr;
            int txx = x0 - 4 + cc;
            if (txx < 0) txx = -1 - txx;
            float v = 0.f;
            if (vy >= 0 && vy < Hd && txx < Wd) {
                size_t o = (size_t)vy * Wd + txx;
                float s0 = 0.f, s1 = 0.f;
                #pragma unroll
                for (int t = 0; t < 4; ++t) {
                    s0 = fmaf(g.w[2*t+1], dn0[(size_t)(j0 + t) * Md + o], s0);
                    s1 = fmaf(g.w[2*t+1], dn1[(size_t)(j0 + t) * Md + o], s1);
                }
                v = 8.f * (g.A*s0 + g.B*s1);
            }
            vt[rr][cc] = v;
        }
    } else {
        for (int i = tid; i < 20*72; i += 256) {
            int rr = i / 72, cc = i - rr*72;
            int vy = vy0 + rr;
            int txx = x0 - 4 + cc;
            if (txx < 0) txx = -1 - txx;
            float v = 0.f;
            if (vy >= 0 && vy < Hd && txx < Wd) {
                size_t o = (size_t)vy * Wd + txx;
                float s0 = 0.f, s1 = 0.f;
                #pragma unroll
                for (int k = 0; k < 9; ++k) {
                    int zk = ridx(z - 4 + k, D);
                    if (!(zk & 1)) {
                        int j = zk >> 1;
                        s0 = fmaf(g.w[k], dn0[(size_t)j * Md + o], s0);
                        s1 = fmaf(g.w[k], dn1[(size_t)j * Md + o], s1);
                    }
                }
                v = 8.f * (g.A*s0 + g.B*s1);
            }
            vt[rr][cc] = v;
        }
    }
    __syncthreads();
    // --- W-filter ---
    for (int i = tid; i < 20*64; i += 256) {
        int rr = i >> 6, c = i & 63;
        float sv = 0.f;
        #pragma unroll
        for (int k = 0; k < 9; ++k) sv = fmaf(g.w[k], vt[rr][c + k], sv);
        mid[rr][c] = sv;
    }
    __syncthreads();
    // --- H-filter (even-row parity) + |cur - up| ---
    const bool yin = (y0 >= 4) && (y0 + 35 < H);
    const int c = tid & 63;
    const int ry_base = (tid >> 6) * 8;
    const int ox = x0 + c;
    const size_t c_off = (size_t)s * H * W;
    const float* curl = (l >= 1) ? p.cur[l] : nullptr;
    float lsum = 0.f;
    #pragma unroll
    for (int j = 0; j < 8; ++j) {
        int ry = ry_base + j;        // parity(ry) == parity(j)
        int oy = y0 + ry;
        if (ox < W && oy < H) {
            float sv = 0.f;
            if (yin) {
                if (!(j & 1)) {
                    int r0 = ry >> 1;
                    sv = g.w[0]*mid[r0][c] + g.w[2]*mid[r0+1][c] + g.w[4]*mid[r0+2][c]
                       + g.w[6]*mid[r0+3][c] + g.w[8]*mid[r0+4][c];
                } else {
                    int r0 = ((ry - 3) >> 1) + 2;
                    sv = g.w[1]*mid[r0][c] + g.w[3]*mid[r0+1][c]
                       + g.w[5]*mid[r0+2][c] + g.w[7]*mid[r0+3][c];
                }
            } else {
                #pragma unroll
                for (int k = 0; k < 9; ++k) {
                    int gy = ridx(oy - 4 + k, H);
                    if (!(gy & 1)) sv = fmaf(g.w[k], mid[(gy >> 1) - vy0][c], sv);
                }
            }
            size_t idx = c_off + (size_t)oy * W + ox;
            float cv;
            if (l == 0) cv = p.use_diff ? __bfloat162float(p.DIFF[idx])
                                        : (p.in[idx] - p.tg[idx]);
            else        cv = curl[idx];
            lsum += fabsf(cv - sv);
        }
    }
    float tot = block_sum256(lsum);
    if (tid == 0) p.P[bid] = tot / ((float)(2*D) * H * W);
}

// ---------------------------------------------------------------------------
__global__ __launch_bounds__(1024)
void kreduce(const float* __restrict__ P, int n, float* __restrict__ out)
{
    float s = 0.f;
    for (int i = threadIdx.x; i < n; i += 1024) s += P[i];
    #pragma unroll
    for (int off = 32; off > 0; off >>= 1) s += __shfl_down(s, off, 64);
    __shared__ float wp[16];
    if ((threadIdx.x & 63) == 0) wp[threadIdx.x >> 6] = s;
    __syncthreads();
    if (threadIdx.x == 0) {
        float t = 0.f;
        #pragma unroll
        for (int w = 0; w < 16; ++w) t += wp[w];
        out[0] = t;
    }
}

// ---------------------------------------------------------------------------
extern "C" void kernel_launch(void* const* d_in, const int* in_sizes, int n_in,
                              void* d_out, int out_size, void* d_ws, size_t ws_size,
                              hipStream_t stream)
{
    const float* in = (const float*)d_in[0];
    const float* tg = (const float*)d_in[1];
    float* out = (float*)d_out;

    GW g;
    {
        double u[9], S = 0.0;
        for (int k = 0; k < 9; ++k) { double d = k - 4; u[k] = exp(-0.5 * d * d); S += u[k]; }
        for (int k = 0; k < 9; ++k) g.w[k] = (float)(u[k] / S);
        g.A = (float)((2.0*u[0] + u[1] + u[3] + u[4]) / S);  // batch(2) reflect self-weight
        g.B = (float)((u[1] + 2.0*u[2] + u[3]) / S);         // cross-weight
    }

    // workspace layout (floats)
    float* T1 = (float*)d_ws;          // 2*64*128*128 = 2097152
    float* C1 = T1 + 2097152;          // 2*32*128*128 = 1048576
    float* C2 = C1 + 1048576;          // 2*16*64*64   = 131072
    float* C3 = C2 + 131072;           // 2*8*32*32    = 16384
    float* C4 = C3 + 16384;            // 2*4*16*16    = 2048
    float* C5 = C4 + 2048;             // 2*2*8*8      = 256
    float* P  = C5 + 256;              // partials, cap 8192
    const int np_cap = 8192;
    __hip_bfloat16* DIFF = (__hip_bfloat16*)(P + np_cap);
    const size_t base_bytes = ((size_t)(P - T1) + np_cap) * sizeof(float);
    const size_t diff_bytes = (size_t)2 * 64 * 256 * 256 * sizeof(__hip_bfloat16);
    const int use_diff = (ws_size >= base_bytes + diff_bytes) ? 1 : 0;

    dim3 blk(256);

    // L1: k1(0) (+bf16 DIFF)
    if (use_diff) k1l0<true ><<<dim3(2,8,128), blk, 0, stream>>>(in, tg, T1, DIFF, g);
    else          k1l0<false><<<dim3(2,8,128), blk, 0, stream>>>(in, tg, T1, nullptr, g);

    // L2: k2(0): T1 -> C1   (D=64, Dd=32, M4=128*128/4=4096)
    k2l0<<<dim3((32*4096 + 255)/256), blk, 0, stream>>>(T1, C1, 64, 32, 4096, g);

    // L3-L6: fused downsample chain for small levels
    k12<<<dim3(1,8,16), blk, 0, stream>>>(C1, C2, 32, 128, 128, g);
    k12<<<dim3(1,4, 8), blk, 0, stream>>>(C2, C3, 16,  64,  64, g);
    k12<<<dim3(1,2, 4), blk, 0, stream>>>(C3, C4,  8,  32,  32, g);
    k12<<<dim3(1,1, 2), blk, 0, stream>>>(C4, C5,  4,  16,  16, g);

    // L7: all levels' loss in one launch
    K4P prm;
    prm.dn[0] = C1; prm.dn[1] = C2; prm.dn[2] = C3; prm.dn[3] = C4; prm.dn[4] = C5;
    prm.cur[0] = nullptr; prm.cur[1] = C1; prm.cur[2] = C2; prm.cur[3] = C3; prm.cur[4] = C4;
    prm.in = in; prm.tg = tg;
    prm.DIFF = use_diff ? DIFF : nullptr;
    prm.P = P; prm.use_diff = use_diff;
    prm.g = g;
    // block counts: l0: 4*8*128=4096, l1: 2*4*64=512, l2: 1*2*32=64, l3: 16, l4: 8
    prm.bo[0] = 0; prm.bo[1] = 4096; prm.bo[2] = 4608;
    prm.bo[3] = 4672; prm.bo[4] = 4688; prm.bo[5] = 4696;
    k4p<<<dim3(4696), blk, 0, stream>>>(prm);

    // L8: final reduce
    kreduce<<<1, 1024, 0, stream>>>(P, 4696, out);
}